// Round 7
// baseline (549.687 us; speedup 1.0000x reference)
//
#include <hip/hip_runtime.h>
#include <hip/hip_bf16.h>
#include <cmath>

#define NLV 16
#define TBL_SIZE (1u << 19)

struct LevelConsts {
    float scale[NLV];
    int   res[NLV];
    int   dense[NLV];
};

// ---------- bf16 helpers ----------
__device__ __forceinline__ unsigned int f32_to_bf16_rne(float f) {
    unsigned int u = __float_as_uint(f);
    return (u + 0x7FFFu + ((u >> 16) & 1u)) >> 16;
}
__device__ __forceinline__ unsigned int pack_bf16(float a, float b) {
    return f32_to_bf16_rne(a) | (f32_to_bf16_rne(b) << 16);
}
__device__ __forceinline__ short f32_to_bf16_s(float f) {
    return (short)f32_to_bf16_rne(f);
}
__device__ __forceinline__ float bf16lo_to_f32(unsigned int g) {
    return __uint_as_float(g << 16);
}
__device__ __forceinline__ float bf16hi_to_f32(unsigned int g) {
    return __uint_as_float(g & 0xFFFF0000u);
}

typedef __attribute__((ext_vector_type(8))) short bf16x8;
typedef __attribute__((ext_vector_type(4))) float f32x4;
typedef __attribute__((ext_vector_type(2))) unsigned int u32x2;

// ---------- kernel A: fp32 table -> packed bf16 pairs ----------
__global__ __launch_bounds__(256) void cvt_table(const float* __restrict__ in,
                                                 unsigned int* __restrict__ out, int npairs) {
    int n2 = npairs >> 1;
    int i = blockIdx.x * 256 + threadIdx.x;
    int stride = gridDim.x * 256;
    const f32x4* in4 = (const f32x4*)in;
    u32x2* out2 = (u32x2*)out;
    for (; i < n2; i += stride) {
        f32x4 v = __builtin_nontemporal_load(&in4[i]);
        u32x2 o;
        o.x = pack_bf16(v.x, v.y);
        o.y = pack_bf16(v.z, v.w);
        __builtin_nontemporal_store(o, &out2[i]);
    }
}

// ---------- kernel B: level-major hash-grid encode ----------
// grid = (chunks, NLV); level-major keeps live table working set L2-resident.
// x-paired 8B gathers (x-prime == 1). Points staged via LDS (coalesced float4)
// to kill redundant per-level point-load L2 requests. Extra (unpaired) corner
// load is exec-masked so paired lanes issue no address.
#define ENC_P 4   // points per thread; 1024 points per block
__global__ __launch_bounds__(256) void encode_lvl(
    const float* __restrict__ points,
    const unsigned int* __restrict__ tbl,
    unsigned int* __restrict__ enc,         // [NLV][N] packed bf16 pairs
    int N, LevelConsts C)
{
    __shared__ __align__(16) float spts[3072];   // 1024 points * 3

    const int level = blockIdx.y;
    const float sc    = C.scale[level];
    const int   res   = C.res[level];
    const int   dense = C.dense[level];
    const unsigned int* __restrict__ t = tbl + (size_t)level * TBL_SIZE;
    unsigned int* __restrict__ eo = enc + (size_t)level * N;

    const int blockBase = blockIdx.x * 1024;

    // ---- stage this block's points into LDS (coalesced) ----
    {
        const float* src = points + (size_t)blockBase * 3;
        long long nfl = (long long)N * 3 - (long long)blockBase * 3;
        if (nfl >= 3072) {
            const float4* s4 = (const float4*)src;
            float4* d4 = (float4*)spts;
            for (int i = threadIdx.x; i < 768; i += 256) d4[i] = s4[i];
        } else {
            for (int i = threadIdx.x; i < 3072; i += 256)
                spts[i] = (i < nfl) ? src[i] : 0.0f;
        }
    }
    __syncthreads();

    int   pt[ENC_P];
    int   valid[ENC_P];
    float wx[ENC_P], wy[ENC_P], wz[ENC_P];
    unsigned int i0a[ENC_P][4], i1a[ENC_P][4];

#pragma unroll
    for (int q = 0; q < ENC_P; q++) {
        int loc = threadIdx.x + q * 256;
        pt[q] = blockBase + loc;
        valid[q] = pt[q] < N;
        float px = spts[loc * 3 + 0];
        float py = spts[loc * 3 + 1];
        float pz = spts[loc * 3 + 2];
        float x = fminf(fmaxf((px + 1.0f) * 0.5f, 0.0f), 1.0f);
        float y = fminf(fmaxf((py + 1.0f) * 0.5f, 0.0f), 1.0f);
        float z = fminf(fmaxf((pz + 1.0f) * 0.5f, 0.0f), 1.0f);

        float fx = x * sc + 0.5f;
        float fy = y * sc + 0.5f;
        float fz = z * sc + 0.5f;
        float f0x = floorf(fx), f0y = floorf(fy), f0z = floorf(fz);
        wx[q] = fx - f0x; wy[q] = fy - f0y; wz[q] = fz - f0z;
        int ix0 = min(max((int)f0x, 0), res - 1);
        int iy0 = min(max((int)f0y, 0), res - 1);
        int iz0 = min(max((int)f0z, 0), res - 1);
        int ix1 = min(ix0 + 1, res - 1);
        int iy1 = min(iy0 + 1, res - 1);
        int iz1 = min(iz0 + 1, res - 1);

        // combos m: bit0 -> y1, bit1 -> z1
#pragma unroll
        for (int m = 0; m < 4; m++) {
            unsigned int uy = (unsigned int)((m & 1) ? iy1 : iy0);
            unsigned int uz = (unsigned int)((m & 2) ? iz1 : iz0);
            unsigned int i0, i1;
            if (dense) {
                unsigned int b = (unsigned int)res * uy + (unsigned int)(res * res) * uz;
                i0 = (unsigned int)ix0 + b;
                i1 = (unsigned int)ix1 + b;
            } else {
                unsigned int H = uy * 2654435761u ^ uz * 805459861u;
                i0 = ((unsigned int)ix0 ^ H) & (TBL_SIZE - 1u);
                i1 = ((unsigned int)ix1 ^ H) & (TBL_SIZE - 1u);
            }
            i0a[q][m] = i0;
            i1a[q][m] = i1;
        }
    }

    // pair loads: always issued, 8B aligned
    u32x2 pr[ENC_P][4];
#pragma unroll
    for (int q = 0; q < ENC_P; q++)
#pragma unroll
        for (int m = 0; m < 4; m++)
            pr[q][m] = *(const u32x2*)(t + (i0a[q][m] & ~1u));

    // extra loads: exec-masked, only unpaired lanes issue an address
    unsigned int ex[ENC_P][4];
#pragma unroll
    for (int q = 0; q < ENC_P; q++)
#pragma unroll
        for (int m = 0; m < 4; m++) {
            unsigned int i0 = i0a[q][m], i1 = i1a[q][m];
            unsigned int v = 0u;
            if (i1 != (i0 ^ 1u)) v = t[i1];
            ex[q][m] = v;
        }

#pragma unroll
    for (int q = 0; q < ENC_P; q++) {
        float e0 = 0.0f, e1 = 0.0f;
        float wxq = wx[q];
#pragma unroll
        for (int m = 0; m < 4; m++) {
            unsigned int i0 = i0a[q][m], i1 = i1a[q][m];
            u32x2 P = pr[q][m];
            unsigned int v0   = (i0 & 1u) ? P.y : P.x;
            unsigned int vpar = (i0 & 1u) ? P.x : P.y;
            unsigned int v1   = (i1 == (i0 ^ 1u)) ? vpar : ex[q][m];
            float wyz = (((m & 1) ? wy[q] : 1.0f - wy[q])) *
                        (((m & 2) ? wz[q] : 1.0f - wz[q]));
            float w0 = wyz * (1.0f - wxq);
            float w1 = wyz * wxq;
            e0 = fmaf(w0, bf16lo_to_f32(v0), e0);
            e0 = fmaf(w1, bf16lo_to_f32(v1), e0);
            e1 = fmaf(w0, bf16hi_to_f32(v0), e1);
            e1 = fmaf(w1, bf16hi_to_f32(v1), e1);
        }
        if (valid[q]) __builtin_nontemporal_store(pack_bf16(e0, e1), &eo[pt[q]]);
    }
}

// ---------- kernel C: persistent fused dual-MLP via MFMA ----------
__global__ __launch_bounds__(256) void mlp_kernel(
    const unsigned int* __restrict__ enc,   // [NLV][N] packed bf16 pairs
    const float* __restrict__ dw1, const float* __restrict__ dw2,
    const float* __restrict__ fw1, const float* __restrict__ fw2,
    float* __restrict__ out, int N, int ntiles)
{
    __shared__ float sW1[128][33];          // combined W1^T, padded
    __shared__ float sw2d[64];
    __shared__ float sw2f[192];
    __shared__ short hsh[4][16][136];       // per-wave h tile
    __shared__ float sOut[4][64];           // per-wave epilogue staging

    const int tid  = threadIdx.x;
    const int wave = tid >> 6;
    const int lane = tid & 63;
    const int l15 = lane & 15;
    const int quad = lane >> 4;

    // coalesced weight staging (once per block)
    for (int e = tid; e < 2048; e += 256) {
        int row = e >> 6, col = e & 63;
        sW1[col][row]      = dw1[e];
        sW1[64 + col][row] = fw1[e];
    }
    if (tid < 64)  sw2d[tid] = dw2[tid];
    if (tid < 192) sw2f[tid] = fw2[tid];
    __syncthreads();

    // B1 fragments from LDS: W1[k][n], element j holds k = quad*8+j, n = 16nt+l15
    bf16x8 B1[8];
#pragma unroll
    for (int nt = 0; nt < 8; nt++) {
#pragma unroll
        for (int j = 0; j < 8; j++)
            B1[nt][j] = f32_to_bf16_s(sW1[nt * 16 + l15][quad * 8 + j]);
    }

    // B2 fragments: combined W2 [128 x 16] block-diagonal zero-padded
    bf16x8 B2[4];
#pragma unroll
    for (int s = 0; s < 4; s++) {
#pragma unroll
        for (int j = 0; j < 8; j++) {
            int k = s * 32 + quad * 8 + j;
            float v = 0.0f;
            if (l15 == 0)      v = (k < 64)  ? sw2d[k] : 0.0f;
            else if (l15 < 4)  v = (k >= 64) ? sw2f[(k - 64) * 3 + (l15 - 1)] : 0.0f;
            B2[s][j] = f32_to_bf16_s(v);
        }
    }

    for (int tile = blockIdx.x; tile < ntiles; tile += gridDim.x) {
        const int ptbase = tile * 64 + wave * 16;
        int pt = ptbase + l15;
        int ptc = min(pt, N - 1);

        // A fragment from level-major enc: dword d = quad*4+j holds feats 2d,2d+1
        union { unsigned int u[4]; bf16x8 v; } acvt;
#pragma unroll
        for (int j = 0; j < 4; j++)
            acvt.u[j] = __builtin_nontemporal_load(&enc[(size_t)(quad * 4 + j) * N + ptc]);

        f32x4 acc1[8];
#pragma unroll
        for (int nt = 0; nt < 8; nt++) {
            acc1[nt] = (f32x4){0.0f, 0.0f, 0.0f, 0.0f};
            acc1[nt] = __builtin_amdgcn_mfma_f32_16x16x32_bf16(acvt.v, B1[nt], acc1[nt], 0, 0, 0);
        }

        // ReLU -> bf16 -> LDS (A-operand layout for layer 2); per-wave private
#pragma unroll
        for (int nt = 0; nt < 8; nt++) {
#pragma unroll
            for (int r = 0; r < 4; r++) {
                float h = fmaxf(acc1[nt][r], 0.0f);
                hsh[wave][quad * 4 + r][nt * 16 + l15] = f32_to_bf16_s(h);
            }
        }

        f32x4 acc2 = (f32x4){0.0f, 0.0f, 0.0f, 0.0f};
#pragma unroll
        for (int s = 0; s < 4; s++) {
            bf16x8 a2 = *(const bf16x8*)&hsh[wave][l15][s * 32 + quad * 8];
            acc2 = __builtin_amdgcn_mfma_f32_16x16x32_bf16(a2, B2[s], acc2, 0, 0, 0);
        }

        // stage raw acc2 into LDS: sOut[wave][p16*4 + chan], chan 0=density,1..3=rgb
        if (l15 < 4) {
#pragma unroll
            for (int r = 0; r < 4; r++)
                sOut[wave][(quad * 4 + r) * 4 + l15] = acc2[r];
        }

        // coalesced epilogue: lanes 0..47 -> color (sigmoid), 48..63 -> density
        if (lane < 48) {
            int p16 = lane / 3;
            int c   = lane - p16 * 3;
            int p   = ptbase + p16;
            float v = sOut[wave][p16 * 4 + 1 + c];
            v = 1.0f / (1.0f + expf(-v));
            if (p < N) out[(size_t)ptbase * 3 + lane] = v;
        } else {
            int p16 = lane - 48;
            int p   = ptbase + p16;
            float v = sOut[wave][p16 * 4];
            v = (v > 20.0f) ? v : log1pf(expf(v));
            if (p < N) out[(size_t)3 * N + p] = v;
        }
    }
}

// ---------- fallback: round-1 fused kernel (used only if ws too small) ----------
__global__ __launch_bounds__(256) void nerf_fused(
    const float* __restrict__ points,
    const float* __restrict__ table,
    const float* __restrict__ dw1, const float* __restrict__ dw2,
    const float* __restrict__ fw1, const float* __restrict__ fw2,
    float* __restrict__ out, int N, LevelConsts C)
{
    __shared__ float sD[64 * 32];
    __shared__ float sF[64 * 32];
    __shared__ float sDw2[64];
    __shared__ float sFw2[64 * 3];

    for (int idx = threadIdx.x; idx < 2048; idx += 256) {
        int i = idx >> 6;
        int j = idx & 63;
        sD[j * 32 + i] = dw1[idx];
        sF[j * 32 + i] = fw1[idx];
    }
    if (threadIdx.x < 64)  sDw2[threadIdx.x] = dw2[threadIdx.x];
    if (threadIdx.x < 192) sFw2[threadIdx.x] = fw2[threadIdx.x];
    __syncthreads();

    int gid = blockIdx.x * 256 + threadIdx.x;
    if (gid >= N) return;

    float px = points[gid * 3 + 0];
    float py = points[gid * 3 + 1];
    float pz = points[gid * 3 + 2];
    float x = fminf(fmaxf((px + 1.0f) * 0.5f, 0.0f), 1.0f);
    float y = fminf(fmaxf((py + 1.0f) * 0.5f, 0.0f), 1.0f);
    float z = fminf(fmaxf((pz + 1.0f) * 0.5f, 0.0f), 1.0f);

    float enc[32];

#pragma unroll
    for (int l = 0; l < NLV; l++) {
        const float sc = C.scale[l];
        const int   res = C.res[l];
        const int   dense = C.dense[l];
        const float* __restrict__ tbl = table + (size_t)l * TBL_SIZE * 2;

        float fx = x * sc + 0.5f;
        float fy = y * sc + 0.5f;
        float fz = z * sc + 0.5f;
        float f0x = floorf(fx), f0y = floorf(fy), f0z = floorf(fz);
        float wx = fx - f0x, wy = fy - f0y, wz = fz - f0z;
        int ix0 = min(max((int)f0x, 0), res - 1);
        int iy0 = min(max((int)f0y, 0), res - 1);
        int iz0 = min(max((int)f0z, 0), res - 1);
        int ix1 = min(ix0 + 1, res - 1);
        int iy1 = min(iy0 + 1, res - 1);
        int iz1 = min(iz0 + 1, res - 1);

        float e0 = 0.0f, e1 = 0.0f;
#pragma unroll
        for (int c = 0; c < 8; c++) {
            int cx = (c & 4) ? ix1 : ix0;
            int cy = (c & 2) ? iy1 : iy0;
            int cz = (c & 1) ? iz1 : iz0;
            float wgt = (((c & 4) ? wx : 1.0f - wx) *
                         ((c & 2) ? wy : 1.0f - wy)) *
                         ((c & 1) ? wz : 1.0f - wz);
            unsigned int idx;
            if (dense) {
                idx = (unsigned int)(cx + res * cy + res * res * cz);
            } else {
                idx = ((unsigned int)cx * 1u
                     ^ (unsigned int)cy * 2654435761u
                     ^ (unsigned int)cz * 805459861u) & (TBL_SIZE - 1u);
            }
            const float2 g = *(const float2*)(tbl + (size_t)idx * 2);
            e0 = fmaf(wgt, g.x, e0);
            e1 = fmaf(wgt, g.y, e1);
        }
        enc[2 * l + 0] = e0;
        enc[2 * l + 1] = e1;
    }

    float dacc = 0.0f, c0 = 0.0f, c1 = 0.0f, c2 = 0.0f;
    for (int j = 0; j < 64; j++) {
        float hd = 0.0f, hf = 0.0f;
        const float* __restrict__ colD = &sD[j * 32];
        const float* __restrict__ colF = &sF[j * 32];
#pragma unroll
        for (int i = 0; i < 32; i++) {
            hd = fmaf(enc[i], colD[i], hd);
            hf = fmaf(enc[i], colF[i], hf);
        }
        hd = fmaxf(hd, 0.0f);
        hf = fmaxf(hf, 0.0f);
        dacc = fmaf(hd, sDw2[j], dacc);
        c0 = fmaf(hf, sFw2[j * 3 + 0], c0);
        c1 = fmaf(hf, sFw2[j * 3 + 1], c1);
        c2 = fmaf(hf, sFw2[j * 3 + 2], c2);
    }

    float density = (dacc > 20.0f) ? dacc : log1pf(expf(dacc));
    out[gid * 3 + 0] = 1.0f / (1.0f + expf(-c0));
    out[gid * 3 + 1] = 1.0f / (1.0f + expf(-c1));
    out[gid * 3 + 2] = 1.0f / (1.0f + expf(-c2));
    out[(size_t)3 * N + gid] = density;
}

extern "C" void kernel_launch(void* const* d_in, const int* in_sizes, int n_in,
                              void* d_out, int out_size, void* d_ws, size_t ws_size,
                              hipStream_t stream) {
    const float* points = (const float*)d_in[0];
    const float* table  = (const float*)d_in[1];
    const float* dw1    = (const float*)d_in[2];
    const float* dw2    = (const float*)d_in[3];
    const float* fw1    = (const float*)d_in[4];
    const float* fw2    = (const float*)d_in[5];
    int N = in_sizes[0] / 3;

    LevelConsts C;
    for (int l = 0; l < NLV; l++) {
        double s = 16.0 * pow(1.447269237440378, (double)l) - 1.0;
        C.scale[l] = (float)s;
        int res = (int)ceil(s) + 1;
        C.res[l] = res;
        C.dense[l] = ((long long)res * res * res <= (long long)TBL_SIZE) ? 1 : 0;
    }

    const size_t tbl_bytes = (size_t)NLV * TBL_SIZE * 4;      // 32 MB packed bf16
    const size_t enc_bytes = (size_t)N * NLV * 4;             // 64 MB level-major
    if (ws_size >= tbl_bytes + enc_bytes) {
        unsigned int* tbl_bf16 = (unsigned int*)d_ws;
        unsigned int* enc_ws   = (unsigned int*)((char*)d_ws + tbl_bytes);

        int npairs = NLV * TBL_SIZE;
        cvt_table<<<1024, 256, 0, stream>>>(table, tbl_bf16, npairs);

        int chunks = (N + 1023) / 1024;
        encode_lvl<<<dim3(chunks, NLV), 256, 0, stream>>>(points, tbl_bf16, enc_ws, N, C);

        int ntiles = (N + 63) / 64;
        mlp_kernel<<<4096, 256, 0, stream>>>(enc_ws, dw1, dw2, fw1, fw2,
                                             (float*)d_out, N, ntiles);
    } else {
        int blocks = (N + 255) / 256;
        nerf_fused<<<blocks, 256, 0, stream>>>(points, table, dw1, dw2, fw1, fw2,
                                               (float*)d_out, N, C);
    }
}

// Round 8
// 540.016 us; speedup vs baseline: 1.0179x; 1.0179x over previous
//
#include <hip/hip_runtime.h>
#include <hip/hip_bf16.h>
#include <cmath>

#define NLV 16
#define TBL_SIZE (1u << 19)

struct LevelConsts {
    float scale[NLV];
    int   res[NLV];
    int   dense[NLV];
};

// ---------- bf16 helpers ----------
__device__ __forceinline__ unsigned int f32_to_bf16_rne(float f) {
    unsigned int u = __float_as_uint(f);
    return (u + 0x7FFFu + ((u >> 16) & 1u)) >> 16;
}
__device__ __forceinline__ unsigned int pack_bf16(float a, float b) {
    return f32_to_bf16_rne(a) | (f32_to_bf16_rne(b) << 16);
}
__device__ __forceinline__ short f32_to_bf16_s(float f) {
    return (short)f32_to_bf16_rne(f);
}
__device__ __forceinline__ float bf16lo_to_f32(unsigned int g) {
    return __uint_as_float(g << 16);
}
__device__ __forceinline__ float bf16hi_to_f32(unsigned int g) {
    return __uint_as_float(g & 0xFFFF0000u);
}

typedef __attribute__((ext_vector_type(8))) short bf16x8;
typedef __attribute__((ext_vector_type(4))) float f32x4;
typedef __attribute__((ext_vector_type(2))) unsigned int u32x2;

// ---------- kernel A: fp32 table -> packed bf16 pairs ----------
__global__ __launch_bounds__(256) void cvt_table(const float* __restrict__ in,
                                                 unsigned int* __restrict__ out, int npairs) {
    int n2 = npairs >> 1;
    int i = blockIdx.x * 256 + threadIdx.x;
    int stride = gridDim.x * 256;
    const f32x4* in4 = (const f32x4*)in;
    u32x2* out2 = (u32x2*)out;
    for (; i < n2; i += stride) {
        f32x4 v = __builtin_nontemporal_load(&in4[i]);
        u32x2 o;
        o.x = pack_bf16(v.x, v.y);
        o.y = pack_bf16(v.z, v.w);
        __builtin_nontemporal_store(o, &out2[i]);
    }
}

// ---------- kernel B: level-major hash-grid encode (R6 form) ----------
// grid = (chunks, NLV); level-major keeps the live table working set
// ~2 levels * 2MB -> L2-resident. x-paired 8B gathers (x-prime == 1):
// one aligned 8B load serves both x-corners when they form an even/odd pair;
// the "extra" dword load duplicates the pair address when paired (L1 hit).
#define ENC_P 4   // points per thread
__global__ __launch_bounds__(256) void encode_lvl(
    const float* __restrict__ points,
    const unsigned int* __restrict__ tbl,
    unsigned int* __restrict__ enc,         // [NLV][N] packed bf16 pairs
    int N, LevelConsts C)
{
    const int level = blockIdx.y;
    const float sc    = C.scale[level];
    const int   res   = C.res[level];
    const int   dense = C.dense[level];
    const unsigned int* __restrict__ t = tbl + (size_t)level * TBL_SIZE;
    unsigned int* __restrict__ eo = enc + (size_t)level * N;

    const int base = blockIdx.x * (256 * ENC_P) + threadIdx.x;

    int   pt[ENC_P];
    int   valid[ENC_P];
    float wx[ENC_P], wy[ENC_P], wz[ENC_P];
    unsigned int i0a[ENC_P][4], i1a[ENC_P][4];

#pragma unroll
    for (int q = 0; q < ENC_P; q++) {
        pt[q] = base + q * 256;
        valid[q] = pt[q] < N;
        int p = valid[q] ? pt[q] : 0;
        float px = __builtin_nontemporal_load(&points[p * 3 + 0]);
        float py = __builtin_nontemporal_load(&points[p * 3 + 1]);
        float pz = __builtin_nontemporal_load(&points[p * 3 + 2]);
        float x = fminf(fmaxf((px + 1.0f) * 0.5f, 0.0f), 1.0f);
        float y = fminf(fmaxf((py + 1.0f) * 0.5f, 0.0f), 1.0f);
        float z = fminf(fmaxf((pz + 1.0f) * 0.5f, 0.0f), 1.0f);

        float fx = x * sc + 0.5f;
        float fy = y * sc + 0.5f;
        float fz = z * sc + 0.5f;
        float f0x = floorf(fx), f0y = floorf(fy), f0z = floorf(fz);
        wx[q] = fx - f0x; wy[q] = fy - f0y; wz[q] = fz - f0z;
        int ix0 = min(max((int)f0x, 0), res - 1);
        int iy0 = min(max((int)f0y, 0), res - 1);
        int iz0 = min(max((int)f0z, 0), res - 1);
        int ix1 = min(ix0 + 1, res - 1);
        int iy1 = min(iy0 + 1, res - 1);
        int iz1 = min(iz0 + 1, res - 1);

        // combos m: bit0 -> y1, bit1 -> z1
#pragma unroll
        for (int m = 0; m < 4; m++) {
            unsigned int uy = (unsigned int)((m & 1) ? iy1 : iy0);
            unsigned int uz = (unsigned int)((m & 2) ? iz1 : iz0);
            unsigned int i0, i1;
            if (dense) {
                unsigned int b = (unsigned int)res * uy + (unsigned int)(res * res) * uz;
                i0 = (unsigned int)ix0 + b;
                i1 = (unsigned int)ix1 + b;
            } else {
                unsigned int H = uy * 2654435761u ^ uz * 805459861u;
                i0 = ((unsigned int)ix0 ^ H) & (TBL_SIZE - 1u);
                i1 = ((unsigned int)ix1 ^ H) & (TBL_SIZE - 1u);
            }
            i0a[q][m] = i0;
            i1a[q][m] = i1;
        }
    }

    // issue all loads together: 4 pair loads + 4 extra loads per point
    u32x2       pr[ENC_P][4];
    unsigned int ex[ENC_P][4];
#pragma unroll
    for (int q = 0; q < ENC_P; q++) {
#pragma unroll
        for (int m = 0; m < 4; m++) {
            unsigned int i0 = i0a[q][m], i1 = i1a[q][m];
            pr[q][m] = *(const u32x2*)(t + (i0 & ~1u));
            unsigned int eidx = (i1 == (i0 ^ 1u)) ? i0 : i1;  // dup -> L1 hit
            ex[q][m] = t[eidx];
        }
    }

#pragma unroll
    for (int q = 0; q < ENC_P; q++) {
        float e0 = 0.0f, e1 = 0.0f;
        float wxq = wx[q];
#pragma unroll
        for (int m = 0; m < 4; m++) {
            unsigned int i0 = i0a[q][m], i1 = i1a[q][m];
            u32x2 P = pr[q][m];
            unsigned int v0   = (i0 & 1u) ? P.y : P.x;
            unsigned int vpar = (i0 & 1u) ? P.x : P.y;
            unsigned int v1   = (i1 == (i0 ^ 1u)) ? vpar : ex[q][m];
            float wyz = (((m & 1) ? wy[q] : 1.0f - wy[q])) *
                        (((m & 2) ? wz[q] : 1.0f - wz[q]));
            float w0 = wyz * (1.0f - wxq);
            float w1 = wyz * wxq;
            e0 = fmaf(w0, bf16lo_to_f32(v0), e0);
            e0 = fmaf(w1, bf16lo_to_f32(v1), e0);
            e1 = fmaf(w0, bf16hi_to_f32(v0), e1);
            e1 = fmaf(w1, bf16hi_to_f32(v1), e1);
        }
        if (valid[q]) __builtin_nontemporal_store(pack_bf16(e0, e1), &eo[pt[q]]);
    }
}

// ---------- kernel C: persistent fused dual-MLP via MFMA ----------
// 64 points per wave per tile (4 subtiles of 16); all 16 A-loads issued
// upfront; per-wave-private LDS h-tile reused across subtiles (DS pipe is
// in-order per wave -> no barriers); batched fully-coalesced epilogue.
__global__ __launch_bounds__(256) void mlp_kernel(
    const unsigned int* __restrict__ enc,   // [NLV][N] packed bf16 pairs
    const float* __restrict__ dw1, const float* __restrict__ dw2,
    const float* __restrict__ fw1, const float* __restrict__ fw2,
    float* __restrict__ out, int N, int ntiles)
{
    __shared__ float sW1[128][33];          // combined W1^T, padded
    __shared__ float sw2d[64];
    __shared__ float sw2f[192];
    __shared__ short hsh[4][16][136];       // per-wave h tile (reused per subtile)
    __shared__ float sOut[4][256];          // per-wave epilogue staging [lp][ch]

    const int tid  = threadIdx.x;
    const int wave = tid >> 6;
    const int lane = tid & 63;
    const int l15 = lane & 15;
    const int quad = lane >> 4;

    // coalesced weight staging (once per block)
    for (int e = tid; e < 2048; e += 256) {
        int row = e >> 6, col = e & 63;
        sW1[col][row]      = dw1[e];
        sW1[64 + col][row] = fw1[e];
    }
    if (tid < 64)  sw2d[tid] = dw2[tid];
    if (tid < 192) sw2f[tid] = fw2[tid];
    __syncthreads();

    // B1 fragments: W1[k][n], element j holds k = quad*8+j, n = 16nt+l15
    bf16x8 B1[8];
#pragma unroll
    for (int nt = 0; nt < 8; nt++) {
#pragma unroll
        for (int j = 0; j < 8; j++)
            B1[nt][j] = f32_to_bf16_s(sW1[nt * 16 + l15][quad * 8 + j]);
    }

    // B2 fragments: combined W2 [128 x 16] block-diagonal zero-padded
    bf16x8 B2[4];
#pragma unroll
    for (int s = 0; s < 4; s++) {
#pragma unroll
        for (int j = 0; j < 8; j++) {
            int k = s * 32 + quad * 8 + j;
            float v = 0.0f;
            if (l15 == 0)      v = (k < 64)  ? sw2d[k] : 0.0f;
            else if (l15 < 4)  v = (k >= 64) ? sw2f[(k - 64) * 3 + (l15 - 1)] : 0.0f;
            B2[s][j] = f32_to_bf16_s(v);
        }
    }

    for (int tile = blockIdx.x; tile < ntiles; tile += gridDim.x) {
        const int wbase = tile * 256 + wave * 64;

        // ---- all 16 A-fragment loads upfront (4 subtiles x 4 dwords) ----
        unsigned int au[4][4];
#pragma unroll
        for (int sub = 0; sub < 4; sub++) {
            int ptc = min(wbase + sub * 16 + l15, N - 1);
#pragma unroll
            for (int j = 0; j < 4; j++)
                au[sub][j] = enc[(size_t)(quad * 4 + j) * N + ptc];
        }

#pragma unroll
        for (int sub = 0; sub < 4; sub++) {
            union { unsigned int u[4]; bf16x8 v; } acvt;
#pragma unroll
            for (int j = 0; j < 4; j++) acvt.u[j] = au[sub][j];

            f32x4 acc1[8];
#pragma unroll
            for (int nt = 0; nt < 8; nt++) {
                acc1[nt] = (f32x4){0.0f, 0.0f, 0.0f, 0.0f};
                acc1[nt] = __builtin_amdgcn_mfma_f32_16x16x32_bf16(acvt.v, B1[nt], acc1[nt], 0, 0, 0);
            }

            // ReLU -> bf16 -> LDS (A-operand layout for layer 2)
#pragma unroll
            for (int nt = 0; nt < 8; nt++) {
#pragma unroll
                for (int r = 0; r < 4; r++) {
                    float h = fmaxf(acc1[nt][r], 0.0f);
                    hsh[wave][quad * 4 + r][nt * 16 + l15] = f32_to_bf16_s(h);
                }
            }

            f32x4 acc2 = (f32x4){0.0f, 0.0f, 0.0f, 0.0f};
#pragma unroll
            for (int s = 0; s < 4; s++) {
                bf16x8 a2 = *(const bf16x8*)&hsh[wave][l15][s * 32 + quad * 8];
                acc2 = __builtin_amdgcn_mfma_f32_16x16x32_bf16(a2, B2[s], acc2, 0, 0, 0);
            }

            // stage acc2: sOut[wave][(sub*16 + p16)*4 + ch]; ch0=density,1..3=rgb
            if (l15 < 4) {
#pragma unroll
                for (int r = 0; r < 4; r++)
                    sOut[wave][(sub * 16 + quad * 4 + r) * 4 + l15] = acc2[r];
            }
        }

        // ---- batched coalesced epilogue: 192 colors + 64 densities per wave ----
        long long cmax = ((long long)N - wbase) * 3;   // color flat-index bound
#pragma unroll
        for (int round = 0; round < 3; round++) {
            int f = round * 64 + lane;                  // [0,192)
            int lp = f / 3, c = f - lp * 3;
            float v = sOut[wave][lp * 4 + 1 + c];
            v = 1.0f / (1.0f + expf(-v));
            if (f < cmax) out[(size_t)wbase * 3 + f] = v;
        }
        {
            int p = wbase + lane;
            float v = sOut[wave][lane * 4];
            v = (v > 20.0f) ? v : log1pf(expf(v));
            if (p < N) out[(size_t)3 * N + p] = v;
        }
    }
}

// ---------- fallback: round-1 fused kernel (used only if ws too small) ----------
__global__ __launch_bounds__(256) void nerf_fused(
    const float* __restrict__ points,
    const float* __restrict__ table,
    const float* __restrict__ dw1, const float* __restrict__ dw2,
    const float* __restrict__ fw1, const float* __restrict__ fw2,
    float* __restrict__ out, int N, LevelConsts C)
{
    __shared__ float sD[64 * 32];
    __shared__ float sF[64 * 32];
    __shared__ float sDw2[64];
    __shared__ float sFw2[64 * 3];

    for (int idx = threadIdx.x; idx < 2048; idx += 256) {
        int i = idx >> 6;
        int j = idx & 63;
        sD[j * 32 + i] = dw1[idx];
        sF[j * 32 + i] = fw1[idx];
    }
    if (threadIdx.x < 64)  sDw2[threadIdx.x] = dw2[threadIdx.x];
    if (threadIdx.x < 192) sFw2[threadIdx.x] = fw2[threadIdx.x];
    __syncthreads();

    int gid = blockIdx.x * 256 + threadIdx.x;
    if (gid >= N) return;

    float px = points[gid * 3 + 0];
    float py = points[gid * 3 + 1];
    float pz = points[gid * 3 + 2];
    float x = fminf(fmaxf((px + 1.0f) * 0.5f, 0.0f), 1.0f);
    float y = fminf(fmaxf((py + 1.0f) * 0.5f, 0.0f), 1.0f);
    float z = fminf(fmaxf((pz + 1.0f) * 0.5f, 0.0f), 1.0f);

    float enc[32];

#pragma unroll
    for (int l = 0; l < NLV; l++) {
        const float sc = C.scale[l];
        const int   res = C.res[l];
        const int   dense = C.dense[l];
        const float* __restrict__ tbl = table + (size_t)l * TBL_SIZE * 2;

        float fx = x * sc + 0.5f;
        float fy = y * sc + 0.5f;
        float fz = z * sc + 0.5f;
        float f0x = floorf(fx), f0y = floorf(fy), f0z = floorf(fz);
        float wx = fx - f0x, wy = fy - f0y, wz = fz - f0z;
        int ix0 = min(max((int)f0x, 0), res - 1);
        int iy0 = min(max((int)f0y, 0), res - 1);
        int iz0 = min(max((int)f0z, 0), res - 1);
        int ix1 = min(ix0 + 1, res - 1);
        int iy1 = min(iy0 + 1, res - 1);
        int iz1 = min(iz0 + 1, res - 1);

        float e0 = 0.0f, e1 = 0.0f;
#pragma unroll
        for (int c = 0; c < 8; c++) {
            int cx = (c & 4) ? ix1 : ix0;
            int cy = (c & 2) ? iy1 : iy0;
            int cz = (c & 1) ? iz1 : iz0;
            float wgt = (((c & 4) ? wx : 1.0f - wx) *
                         ((c & 2) ? wy : 1.0f - wy)) *
                         ((c & 1) ? wz : 1.0f - wz);
            unsigned int idx;
            if (dense) {
                idx = (unsigned int)(cx + res * cy + res * res * cz);
            } else {
                idx = ((unsigned int)cx * 1u
                     ^ (unsigned int)cy * 2654435761u
                     ^ (unsigned int)cz * 805459861u) & (TBL_SIZE - 1u);
            }
            const float2 g = *(const float2*)(tbl + (size_t)idx * 2);
            e0 = fmaf(wgt, g.x, e0);
            e1 = fmaf(wgt, g.y, e1);
        }
        enc[2 * l + 0] = e0;
        enc[2 * l + 1] = e1;
    }

    float dacc = 0.0f, c0 = 0.0f, c1 = 0.0f, c2 = 0.0f;
    for (int j = 0; j < 64; j++) {
        float hd = 0.0f, hf = 0.0f;
        const float* __restrict__ colD = &sD[j * 32];
        const float* __restrict__ colF = &sF[j * 32];
#pragma unroll
        for (int i = 0; i < 32; i++) {
            hd = fmaf(enc[i], colD[i], hd);
            hf = fmaf(enc[i], colF[i], hf);
        }
        hd = fmaxf(hd, 0.0f);
        hf = fmaxf(hf, 0.0f);
        dacc = fmaf(hd, sDw2[j], dacc);
        c0 = fmaf(hf, sFw2[j * 3 + 0], c0);
        c1 = fmaf(hf, sFw2[j * 3 + 1], c1);
        c2 = fmaf(hf, sFw2[j * 3 + 2], c2);
    }

    float density = (dacc > 20.0f) ? dacc : log1pf(expf(dacc));
    out[gid * 3 + 0] = 1.0f / (1.0f + expf(-c0));
    out[gid * 3 + 1] = 1.0f / (1.0f + expf(-c1));
    out[gid * 3 + 2] = 1.0f / (1.0f + expf(-c2));
    out[(size_t)3 * N + gid] = density;
}

extern "C" void kernel_launch(void* const* d_in, const int* in_sizes, int n_in,
                              void* d_out, int out_size, void* d_ws, size_t ws_size,
                              hipStream_t stream) {
    const float* points = (const float*)d_in[0];
    const float* table  = (const float*)d_in[1];
    const float* dw1    = (const float*)d_in[2];
    const float* dw2    = (const float*)d_in[3];
    const float* fw1    = (const float*)d_in[4];
    const float* fw2    = (const float*)d_in[5];
    int N = in_sizes[0] / 3;

    LevelConsts C;
    for (int l = 0; l < NLV; l++) {
        double s = 16.0 * pow(1.447269237440378, (double)l) - 1.0;
        C.scale[l] = (float)s;
        int res = (int)ceil(s) + 1;
        C.res[l] = res;
        C.dense[l] = ((long long)res * res * res <= (long long)TBL_SIZE) ? 1 : 0;
    }

    const size_t tbl_bytes = (size_t)NLV * TBL_SIZE * 4;      // 32 MB packed bf16
    const size_t enc_bytes = (size_t)N * NLV * 4;             // 64 MB level-major
    if (ws_size >= tbl_bytes + enc_bytes) {
        unsigned int* tbl_bf16 = (unsigned int*)d_ws;
        unsigned int* enc_ws   = (unsigned int*)((char*)d_ws + tbl_bytes);

        int npairs = NLV * TBL_SIZE;
        cvt_table<<<1024, 256, 0, stream>>>(table, tbl_bf16, npairs);

        int chunks = (N + 256 * ENC_P - 1) / (256 * ENC_P);
        encode_lvl<<<dim3(chunks, NLV), 256, 0, stream>>>(points, tbl_bf16, enc_ws, N, C);

        int ntiles = (N + 255) / 256;
        mlp_kernel<<<1024, 256, 0, stream>>>(enc_ws, dw1, dw2, fw1, fw2,
                                             (float*)d_out, N, ntiles);
    } else {
        int blocks = (N + 255) / 256;
        nerf_fused<<<blocks, 256, 0, stream>>>(points, table, dw1, dw2, fw1, fw2,
                                               (float*)d_out, N, C);
    }
}

// Round 9
// 534.701 us; speedup vs baseline: 1.0280x; 1.0099x over previous
//
#include <hip/hip_runtime.h>
#include <hip/hip_bf16.h>
#include <cmath>

#define NLV 16
#define TBL_SIZE (1u << 19)

struct LevelConsts {
    float scale[NLV];
    int   res[NLV];
    int   dense[NLV];
};

// ---------- bf16 helpers ----------
__device__ __forceinline__ unsigned int f32_to_bf16_rne(float f) {
    unsigned int u = __float_as_uint(f);
    return (u + 0x7FFFu + ((u >> 16) & 1u)) >> 16;
}
__device__ __forceinline__ unsigned int pack_bf16(float a, float b) {
    return f32_to_bf16_rne(a) | (f32_to_bf16_rne(b) << 16);
}
__device__ __forceinline__ short f32_to_bf16_s(float f) {
    return (short)f32_to_bf16_rne(f);
}
__device__ __forceinline__ float bf16lo_to_f32(unsigned int g) {
    return __uint_as_float(g << 16);
}
__device__ __forceinline__ float bf16hi_to_f32(unsigned int g) {
    return __uint_as_float(g & 0xFFFF0000u);
}

typedef __attribute__((ext_vector_type(8))) short bf16x8;
typedef __attribute__((ext_vector_type(4))) float f32x4;
typedef __attribute__((ext_vector_type(2))) unsigned int u32x2;

// ---------- kernel A: fp32 table -> packed bf16 pairs ----------
__global__ __launch_bounds__(256) void cvt_table(const float* __restrict__ in,
                                                 unsigned int* __restrict__ out, int npairs) {
    int n2 = npairs >> 1;
    int i = blockIdx.x * 256 + threadIdx.x;
    int stride = gridDim.x * 256;
    const f32x4* in4 = (const f32x4*)in;
    u32x2* out2 = (u32x2*)out;
    for (; i < n2; i += stride) {
        f32x4 v = __builtin_nontemporal_load(&in4[i]);
        u32x2 o;
        o.x = pack_bf16(v.x, v.y);
        o.y = pack_bf16(v.z, v.w);
        __builtin_nontemporal_store(o, &out2[i]);
    }
}

// ---------- kernel B: level-major hash-grid encode (R6/R8 form, unchanged) ----
#define ENC_P 4   // points per thread
__global__ __launch_bounds__(256) void encode_lvl(
    const float* __restrict__ points,
    const unsigned int* __restrict__ tbl,
    unsigned int* __restrict__ enc,         // [NLV][N] packed bf16 pairs
    int N, LevelConsts C)
{
    const int level = blockIdx.y;
    const float sc    = C.scale[level];
    const int   res   = C.res[level];
    const int   dense = C.dense[level];
    const unsigned int* __restrict__ t = tbl + (size_t)level * TBL_SIZE;
    unsigned int* __restrict__ eo = enc + (size_t)level * N;

    const int base = blockIdx.x * (256 * ENC_P) + threadIdx.x;

    int   pt[ENC_P];
    int   valid[ENC_P];
    float wx[ENC_P], wy[ENC_P], wz[ENC_P];
    unsigned int i0a[ENC_P][4], i1a[ENC_P][4];

#pragma unroll
    for (int q = 0; q < ENC_P; q++) {
        pt[q] = base + q * 256;
        valid[q] = pt[q] < N;
        int p = valid[q] ? pt[q] : 0;
        float px = __builtin_nontemporal_load(&points[p * 3 + 0]);
        float py = __builtin_nontemporal_load(&points[p * 3 + 1]);
        float pz = __builtin_nontemporal_load(&points[p * 3 + 2]);
        float x = fminf(fmaxf((px + 1.0f) * 0.5f, 0.0f), 1.0f);
        float y = fminf(fmaxf((py + 1.0f) * 0.5f, 0.0f), 1.0f);
        float z = fminf(fmaxf((pz + 1.0f) * 0.5f, 0.0f), 1.0f);

        float fx = x * sc + 0.5f;
        float fy = y * sc + 0.5f;
        float fz = z * sc + 0.5f;
        float f0x = floorf(fx), f0y = floorf(fy), f0z = floorf(fz);
        wx[q] = fx - f0x; wy[q] = fy - f0y; wz[q] = fz - f0z;
        int ix0 = min(max((int)f0x, 0), res - 1);
        int iy0 = min(max((int)f0y, 0), res - 1);
        int iz0 = min(max((int)f0z, 0), res - 1);
        int ix1 = min(ix0 + 1, res - 1);
        int iy1 = min(iy0 + 1, res - 1);
        int iz1 = min(iz0 + 1, res - 1);

#pragma unroll
        for (int m = 0; m < 4; m++) {
            unsigned int uy = (unsigned int)((m & 1) ? iy1 : iy0);
            unsigned int uz = (unsigned int)((m & 2) ? iz1 : iz0);
            unsigned int i0, i1;
            if (dense) {
                unsigned int b = (unsigned int)res * uy + (unsigned int)(res * res) * uz;
                i0 = (unsigned int)ix0 + b;
                i1 = (unsigned int)ix1 + b;
            } else {
                unsigned int H = uy * 2654435761u ^ uz * 805459861u;
                i0 = ((unsigned int)ix0 ^ H) & (TBL_SIZE - 1u);
                i1 = ((unsigned int)ix1 ^ H) & (TBL_SIZE - 1u);
            }
            i0a[q][m] = i0;
            i1a[q][m] = i1;
        }
    }

    u32x2       pr[ENC_P][4];
    unsigned int ex[ENC_P][4];
#pragma unroll
    for (int q = 0; q < ENC_P; q++) {
#pragma unroll
        for (int m = 0; m < 4; m++) {
            unsigned int i0 = i0a[q][m], i1 = i1a[q][m];
            pr[q][m] = *(const u32x2*)(t + (i0 & ~1u));
            unsigned int eidx = (i1 == (i0 ^ 1u)) ? i0 : i1;  // dup -> L1 hit
            ex[q][m] = t[eidx];
        }
    }

#pragma unroll
    for (int q = 0; q < ENC_P; q++) {
        float e0 = 0.0f, e1 = 0.0f;
        float wxq = wx[q];
#pragma unroll
        for (int m = 0; m < 4; m++) {
            unsigned int i0 = i0a[q][m], i1 = i1a[q][m];
            u32x2 P = pr[q][m];
            unsigned int v0   = (i0 & 1u) ? P.y : P.x;
            unsigned int vpar = (i0 & 1u) ? P.x : P.y;
            unsigned int v1   = (i1 == (i0 ^ 1u)) ? vpar : ex[q][m];
            float wyz = (((m & 1) ? wy[q] : 1.0f - wy[q])) *
                        (((m & 2) ? wz[q] : 1.0f - wz[q]));
            float w0 = wyz * (1.0f - wxq);
            float w1 = wyz * wxq;
            e0 = fmaf(w0, bf16lo_to_f32(v0), e0);
            e0 = fmaf(w1, bf16lo_to_f32(v1), e0);
            e1 = fmaf(w0, bf16hi_to_f32(v0), e1);
            e1 = fmaf(w1, bf16hi_to_f32(v1), e1);
        }
        if (valid[q]) __builtin_nontemporal_store(pack_bf16(e0, e1), &eo[pt[q]]);
    }
}

// ---------- kernel C: persistent fused dual-MLP via MFMA ----------
// LDS-lean (21.5 KB -> 7 blocks/CU): B-fragments built straight from global
// (once per block, L2-cached). acc2 uses 4 independent accumulators (no serial
// MFMA chain). 64 points per wave per tile, loads upfront, coalesced epilogue.
__global__ __launch_bounds__(256, 4) void mlp_kernel(
    const unsigned int* __restrict__ enc,   // [NLV][N] packed bf16 pairs
    const float* __restrict__ dw1, const float* __restrict__ dw2,
    const float* __restrict__ fw1, const float* __restrict__ fw2,
    float* __restrict__ out, int N, int ntiles)
{
    __shared__ short hsh[4][16][136];       // per-wave h tile (reused per subtile)
    __shared__ float sOut[4][256];          // per-wave epilogue staging [lp][ch]

    const int tid  = threadIdx.x;
    const int wave = tid >> 6;
    const int lane = tid & 63;
    const int l15 = lane & 15;
    const int quad = lane >> 4;

    // B1 fragments straight from global: W1[k][n], k = quad*8+j, n = 16nt+l15
    bf16x8 B1[8];
#pragma unroll
    for (int nt = 0; nt < 8; nt++) {
        int col = nt * 16 + l15;
        const float* w = (col < 64) ? (dw1 + col) : (fw1 + (col - 64));
#pragma unroll
        for (int j = 0; j < 8; j++) {
            int k = quad * 8 + j;
            B1[nt][j] = f32_to_bf16_s(w[k * 64]);
        }
    }

    // B2 fragments: combined W2 [128 x 16] block-diagonal zero-padded
    bf16x8 B2[4];
#pragma unroll
    for (int s = 0; s < 4; s++) {
#pragma unroll
        for (int j = 0; j < 8; j++) {
            int k = s * 32 + quad * 8 + j;
            float v = 0.0f;
            if (l15 == 0)      v = (k < 64)  ? dw2[k] : 0.0f;
            else if (l15 < 4)  v = (k >= 64) ? fw2[(k - 64) * 3 + (l15 - 1)] : 0.0f;
            B2[s][j] = f32_to_bf16_s(v);
        }
    }

    for (int tile = blockIdx.x; tile < ntiles; tile += gridDim.x) {
        const int wbase = tile * 256 + wave * 64;

        // all 16 A-fragment loads upfront (4 subtiles x 4 dwords)
        unsigned int au[4][4];
#pragma unroll
        for (int sub = 0; sub < 4; sub++) {
            int ptc = min(wbase + sub * 16 + l15, N - 1);
#pragma unroll
            for (int j = 0; j < 4; j++)
                au[sub][j] = enc[(size_t)(quad * 4 + j) * N + ptc];
        }

#pragma unroll
        for (int sub = 0; sub < 4; sub++) {
            union { unsigned int u[4]; bf16x8 v; } acvt;
#pragma unroll
            for (int j = 0; j < 4; j++) acvt.u[j] = au[sub][j];

            f32x4 acc1[8];
#pragma unroll
            for (int nt = 0; nt < 8; nt++) {
                acc1[nt] = (f32x4){0.0f, 0.0f, 0.0f, 0.0f};
                acc1[nt] = __builtin_amdgcn_mfma_f32_16x16x32_bf16(acvt.v, B1[nt], acc1[nt], 0, 0, 0);
            }

            // ReLU -> bf16 -> LDS (A-operand layout for layer 2)
#pragma unroll
            for (int nt = 0; nt < 8; nt++) {
#pragma unroll
                for (int r = 0; r < 4; r++) {
                    float h = fmaxf(acc1[nt][r], 0.0f);
                    hsh[wave][quad * 4 + r][nt * 16 + l15] = f32_to_bf16_s(h);
                }
            }

            // layer 2: 4 INDEPENDENT partial MFMAs, summed after (no serial chain)
            f32x4 p0 = (f32x4){0,0,0,0}, p1 = (f32x4){0,0,0,0};
            f32x4 p2 = (f32x4){0,0,0,0}, p3 = (f32x4){0,0,0,0};
            {
                bf16x8 a0 = *(const bf16x8*)&hsh[wave][l15][0 * 32 + quad * 8];
                bf16x8 a1 = *(const bf16x8*)&hsh[wave][l15][1 * 32 + quad * 8];
                bf16x8 a2 = *(const bf16x8*)&hsh[wave][l15][2 * 32 + quad * 8];
                bf16x8 a3 = *(const bf16x8*)&hsh[wave][l15][3 * 32 + quad * 8];
                p0 = __builtin_amdgcn_mfma_f32_16x16x32_bf16(a0, B2[0], p0, 0, 0, 0);
                p1 = __builtin_amdgcn_mfma_f32_16x16x32_bf16(a1, B2[1], p1, 0, 0, 0);
                p2 = __builtin_amdgcn_mfma_f32_16x16x32_bf16(a2, B2[2], p2, 0, 0, 0);
                p3 = __builtin_amdgcn_mfma_f32_16x16x32_bf16(a3, B2[3], p3, 0, 0, 0);
            }
            f32x4 acc2;
#pragma unroll
            for (int r = 0; r < 4; r++) acc2[r] = (p0[r] + p1[r]) + (p2[r] + p3[r]);

            // stage acc2: sOut[wave][(sub*16 + p16)*4 + ch]; ch0=density,1..3=rgb
            if (l15 < 4) {
#pragma unroll
                for (int r = 0; r < 4; r++)
                    sOut[wave][(sub * 16 + quad * 4 + r) * 4 + l15] = acc2[r];
            }
        }

        // batched coalesced epilogue: 192 colors + 64 densities per wave
        long long cmax = ((long long)N - wbase) * 3;
#pragma unroll
        for (int round = 0; round < 3; round++) {
            int f = round * 64 + lane;
            int lp = f / 3, c = f - lp * 3;
            float v = sOut[wave][lp * 4 + 1 + c];
            v = 1.0f / (1.0f + expf(-v));
            if (f < cmax) out[(size_t)wbase * 3 + f] = v;
        }
        {
            int p = wbase + lane;
            float v = sOut[wave][lane * 4];
            v = (v > 20.0f) ? v : log1pf(expf(v));
            if (p < N) out[(size_t)3 * N + p] = v;
        }
    }
}

// ---------- fallback: round-1 fused kernel (used only if ws too small) ----------
__global__ __launch_bounds__(256) void nerf_fused(
    const float* __restrict__ points,
    const float* __restrict__ table,
    const float* __restrict__ dw1, const float* __restrict__ dw2,
    const float* __restrict__ fw1, const float* __restrict__ fw2,
    float* __restrict__ out, int N, LevelConsts C)
{
    __shared__ float sD[64 * 32];
    __shared__ float sF[64 * 32];
    __shared__ float sDw2[64];
    __shared__ float sFw2[64 * 3];

    for (int idx = threadIdx.x; idx < 2048; idx += 256) {
        int i = idx >> 6;
        int j = idx & 63;
        sD[j * 32 + i] = dw1[idx];
        sF[j * 32 + i] = fw1[idx];
    }
    if (threadIdx.x < 64)  sDw2[threadIdx.x] = dw2[threadIdx.x];
    if (threadIdx.x < 192) sFw2[threadIdx.x] = fw2[threadIdx.x];
    __syncthreads();

    int gid = blockIdx.x * 256 + threadIdx.x;
    if (gid >= N) return;

    float px = points[gid * 3 + 0];
    float py = points[gid * 3 + 1];
    float pz = points[gid * 3 + 2];
    float x = fminf(fmaxf((px + 1.0f) * 0.5f, 0.0f), 1.0f);
    float y = fminf(fmaxf((py + 1.0f) * 0.5f, 0.0f), 1.0f);
    float z = fminf(fmaxf((pz + 1.0f) * 0.5f, 0.0f), 1.0f);

    float enc[32];

#pragma unroll
    for (int l = 0; l < NLV; l++) {
        const float sc = C.scale[l];
        const int   res = C.res[l];
        const int   dense = C.dense[l];
        const float* __restrict__ tbl = table + (size_t)l * TBL_SIZE * 2;

        float fx = x * sc + 0.5f;
        float fy = y * sc + 0.5f;
        float fz = z * sc + 0.5f;
        float f0x = floorf(fx), f0y = floorf(fy), f0z = floorf(fz);
        float wx = fx - f0x, wy = fy - f0y, wz = fz - f0z;
        int ix0 = min(max((int)f0x, 0), res - 1);
        int iy0 = min(max((int)f0y, 0), res - 1);
        int iz0 = min(max((int)f0z, 0), res - 1);
        int ix1 = min(ix0 + 1, res - 1);
        int iy1 = min(iy0 + 1, res - 1);
        int iz1 = min(iz0 + 1, res - 1);

        float e0 = 0.0f, e1 = 0.0f;
#pragma unroll
        for (int c = 0; c < 8; c++) {
            int cx = (c & 4) ? ix1 : ix0;
            int cy = (c & 2) ? iy1 : iy0;
            int cz = (c & 1) ? iz1 : iz0;
            float wgt = (((c & 4) ? wx : 1.0f - wx) *
                         ((c & 2) ? wy : 1.0f - wy)) *
                         ((c & 1) ? wz : 1.0f - wz);
            unsigned int idx;
            if (dense) {
                idx = (unsigned int)(cx + res * cy + res * res * cz);
            } else {
                idx = ((unsigned int)cx * 1u
                     ^ (unsigned int)cy * 2654435761u
                     ^ (unsigned int)cz * 805459861u) & (TBL_SIZE - 1u);
            }
            const float2 g = *(const float2*)(tbl + (size_t)idx * 2);
            e0 = fmaf(wgt, g.x, e0);
            e1 = fmaf(wgt, g.y, e1);
        }
        enc[2 * l + 0] = e0;
        enc[2 * l + 1] = e1;
    }

    float dacc = 0.0f, c0 = 0.0f, c1 = 0.0f, c2 = 0.0f;
    for (int j = 0; j < 64; j++) {
        float hd = 0.0f, hf = 0.0f;
        const float* __restrict__ colD = &sD[j * 32];
        const float* __restrict__ colF = &sF[j * 32];
#pragma unroll
        for (int i = 0; i < 32; i++) {
            hd = fmaf(enc[i], colD[i], hd);
            hf = fmaf(enc[i], colF[i], hf);
        }
        hd = fmaxf(hd, 0.0f);
        hf = fmaxf(hf, 0.0f);
        dacc = fmaf(hd, sDw2[j], dacc);
        c0 = fmaf(hf, sFw2[j * 3 + 0], c0);
        c1 = fmaf(hf, sFw2[j * 3 + 1], c1);
        c2 = fmaf(hf, sFw2[j * 3 + 2], c2);
    }

    float density = (dacc > 20.0f) ? dacc : log1pf(expf(dacc));
    out[gid * 3 + 0] = 1.0f / (1.0f + expf(-c0));
    out[gid * 3 + 1] = 1.0f / (1.0f + expf(-c1));
    out[gid * 3 + 2] = 1.0f / (1.0f + expf(-c2));
    out[(size_t)3 * N + gid] = density;
}

extern "C" void kernel_launch(void* const* d_in, const int* in_sizes, int n_in,
                              void* d_out, int out_size, void* d_ws, size_t ws_size,
                              hipStream_t stream) {
    const float* points = (const float*)d_in[0];
    const float* table  = (const float*)d_in[1];
    const float* dw1    = (const float*)d_in[2];
    const float* dw2    = (const float*)d_in[3];
    const float* fw1    = (const float*)d_in[4];
    const float* fw2    = (const float*)d_in[5];
    int N = in_sizes[0] / 3;

    LevelConsts C;
    for (int l = 0; l < NLV; l++) {
        double s = 16.0 * pow(1.447269237440378, (double)l) - 1.0;
        C.scale[l] = (float)s;
        int res = (int)ceil(s) + 1;
        C.res[l] = res;
        C.dense[l] = ((long long)res * res * res <= (long long)TBL_SIZE) ? 1 : 0;
    }

    const size_t tbl_bytes = (size_t)NLV * TBL_SIZE * 4;      // 32 MB packed bf16
    const size_t enc_bytes = (size_t)N * NLV * 4;             // 64 MB level-major
    if (ws_size >= tbl_bytes + enc_bytes) {
        unsigned int* tbl_bf16 = (unsigned int*)d_ws;
        unsigned int* enc_ws   = (unsigned int*)((char*)d_ws + tbl_bytes);

        int npairs = NLV * TBL_SIZE;
        cvt_table<<<1024, 256, 0, stream>>>(table, tbl_bf16, npairs);

        int chunks = (N + 256 * ENC_P - 1) / (256 * ENC_P);
        encode_lvl<<<dim3(chunks, NLV), 256, 0, stream>>>(points, tbl_bf16, enc_ws, N, C);

        int ntiles = (N + 255) / 256;
        mlp_kernel<<<1792, 256, 0, stream>>>(enc_ws, dw1, dw2, fw1, fw2,
                                             (float*)d_out, N, ntiles);
    } else {
        int blocks = (N + 255) / 256;
        nerf_fused<<<blocks, 256, 0, stream>>>(points, table, dw1, dw2, fw1, fw2,
                                               (float*)d_out, N, C);
    }
}

// Round 10
// 533.221 us; speedup vs baseline: 1.0309x; 1.0028x over previous
//
#include <hip/hip_runtime.h>
#include <hip/hip_bf16.h>
#include <cmath>

#define NLV 16
#define TBL_SIZE (1u << 19)

struct LevelConsts {
    float scale[NLV];
    int   res[NLV];
    int   dense[NLV];
};

// ---------- bf16 helpers ----------
__device__ __forceinline__ unsigned int f32_to_bf16_rne(float f) {
    unsigned int u = __float_as_uint(f);
    return (u + 0x7FFFu + ((u >> 16) & 1u)) >> 16;
}
__device__ __forceinline__ unsigned int pack_bf16(float a, float b) {
    return f32_to_bf16_rne(a) | (f32_to_bf16_rne(b) << 16);
}
__device__ __forceinline__ short f32_to_bf16_s(float f) {
    return (short)f32_to_bf16_rne(f);
}
__device__ __forceinline__ float bf16lo_to_f32(unsigned int g) {
    return __uint_as_float(g << 16);
}
__device__ __forceinline__ float bf16hi_to_f32(unsigned int g) {
    return __uint_as_float(g & 0xFFFF0000u);
}

typedef __attribute__((ext_vector_type(8))) short bf16x8;
typedef __attribute__((ext_vector_type(4))) float f32x4;
typedef __attribute__((ext_vector_type(2))) unsigned int u32x2;
typedef __attribute__((ext_vector_type(4))) unsigned int u32x4;

// ---------- kernel A: fp32 table -> packed bf16 pairs ----------
__global__ __launch_bounds__(256) void cvt_table(const float* __restrict__ in,
                                                 unsigned int* __restrict__ out, int npairs) {
    int n2 = npairs >> 1;
    int i = blockIdx.x * 256 + threadIdx.x;
    int stride = gridDim.x * 256;
    const f32x4* in4 = (const f32x4*)in;
    u32x2* out2 = (u32x2*)out;
    for (; i < n2; i += stride) {
        f32x4 v = __builtin_nontemporal_load(&in4[i]);
        u32x2 o;
        o.x = pack_bf16(v.x, v.y);
        o.y = pack_bf16(v.z, v.w);
        __builtin_nontemporal_store(o, &out2[i]);
    }
}

// ---------- kernel B: level-major hash-grid encode (R6/R8 form, unchanged) ----
#define ENC_P 4   // points per thread
__global__ __launch_bounds__(256) void encode_lvl(
    const float* __restrict__ points,
    const unsigned int* __restrict__ tbl,
    unsigned int* __restrict__ enc,         // [NLV][N] packed bf16 pairs
    int N, LevelConsts C)
{
    const int level = blockIdx.y;
    const float sc    = C.scale[level];
    const int   res   = C.res[level];
    const int   dense = C.dense[level];
    const unsigned int* __restrict__ t = tbl + (size_t)level * TBL_SIZE;
    unsigned int* __restrict__ eo = enc + (size_t)level * N;

    const int base = blockIdx.x * (256 * ENC_P) + threadIdx.x;

    int   pt[ENC_P];
    int   valid[ENC_P];
    float wx[ENC_P], wy[ENC_P], wz[ENC_P];
    unsigned int i0a[ENC_P][4], i1a[ENC_P][4];

#pragma unroll
    for (int q = 0; q < ENC_P; q++) {
        pt[q] = base + q * 256;
        valid[q] = pt[q] < N;
        int p = valid[q] ? pt[q] : 0;
        float px = __builtin_nontemporal_load(&points[p * 3 + 0]);
        float py = __builtin_nontemporal_load(&points[p * 3 + 1]);
        float pz = __builtin_nontemporal_load(&points[p * 3 + 2]);
        float x = fminf(fmaxf((px + 1.0f) * 0.5f, 0.0f), 1.0f);
        float y = fminf(fmaxf((py + 1.0f) * 0.5f, 0.0f), 1.0f);
        float z = fminf(fmaxf((pz + 1.0f) * 0.5f, 0.0f), 1.0f);

        float fx = x * sc + 0.5f;
        float fy = y * sc + 0.5f;
        float fz = z * sc + 0.5f;
        float f0x = floorf(fx), f0y = floorf(fy), f0z = floorf(fz);
        wx[q] = fx - f0x; wy[q] = fy - f0y; wz[q] = fz - f0z;
        int ix0 = min(max((int)f0x, 0), res - 1);
        int iy0 = min(max((int)f0y, 0), res - 1);
        int iz0 = min(max((int)f0z, 0), res - 1);
        int ix1 = min(ix0 + 1, res - 1);
        int iy1 = min(iy0 + 1, res - 1);
        int iz1 = min(iz0 + 1, res - 1);

#pragma unroll
        for (int m = 0; m < 4; m++) {
            unsigned int uy = (unsigned int)((m & 1) ? iy1 : iy0);
            unsigned int uz = (unsigned int)((m & 2) ? iz1 : iz0);
            unsigned int i0, i1;
            if (dense) {
                unsigned int b = (unsigned int)res * uy + (unsigned int)(res * res) * uz;
                i0 = (unsigned int)ix0 + b;
                i1 = (unsigned int)ix1 + b;
            } else {
                unsigned int H = uy * 2654435761u ^ uz * 805459861u;
                i0 = ((unsigned int)ix0 ^ H) & (TBL_SIZE - 1u);
                i1 = ((unsigned int)ix1 ^ H) & (TBL_SIZE - 1u);
            }
            i0a[q][m] = i0;
            i1a[q][m] = i1;
        }
    }

    u32x2       pr[ENC_P][4];
    unsigned int ex[ENC_P][4];
#pragma unroll
    for (int q = 0; q < ENC_P; q++) {
#pragma unroll
        for (int m = 0; m < 4; m++) {
            unsigned int i0 = i0a[q][m], i1 = i1a[q][m];
            pr[q][m] = *(const u32x2*)(t + (i0 & ~1u));
            unsigned int eidx = (i1 == (i0 ^ 1u)) ? i0 : i1;  // dup -> L1 hit
            ex[q][m] = t[eidx];
        }
    }

#pragma unroll
    for (int q = 0; q < ENC_P; q++) {
        float e0 = 0.0f, e1 = 0.0f;
        float wxq = wx[q];
#pragma unroll
        for (int m = 0; m < 4; m++) {
            unsigned int i0 = i0a[q][m], i1 = i1a[q][m];
            u32x2 P = pr[q][m];
            unsigned int v0   = (i0 & 1u) ? P.y : P.x;
            unsigned int vpar = (i0 & 1u) ? P.x : P.y;
            unsigned int v1   = (i1 == (i0 ^ 1u)) ? vpar : ex[q][m];
            float wyz = (((m & 1) ? wy[q] : 1.0f - wy[q])) *
                        (((m & 2) ? wz[q] : 1.0f - wz[q]));
            float w0 = wyz * (1.0f - wxq);
            float w1 = wyz * wxq;
            e0 = fmaf(w0, bf16lo_to_f32(v0), e0);
            e0 = fmaf(w1, bf16lo_to_f32(v1), e0);
            e1 = fmaf(w0, bf16hi_to_f32(v0), e1);
            e1 = fmaf(w1, bf16hi_to_f32(v1), e1);
        }
        if (valid[q]) __builtin_nontemporal_store(pack_bf16(e0, e1), &eo[pt[q]]);
    }
}

// ---------- kernel C: persistent fused dual-MLP via MFMA ----------
// h-transpose uses a PERMUTED LDS layout: lane's 8 h-values (nt=0..7) stored
// contiguously -> ONE ds_write_b128 per r (4 per subtile) instead of 32
// scattered ds_write_b16. LDS offset o holds hidden unit hu(o)=16*(o&7)+(o>>3);
// B2 rows are built with that permutation.
__global__ __launch_bounds__(256, 4) void mlp_kernel(
    const unsigned int* __restrict__ enc,   // [NLV][N] packed bf16 pairs
    const float* __restrict__ dw1, const float* __restrict__ dw2,
    const float* __restrict__ fw1, const float* __restrict__ fw2,
    float* __restrict__ out, int N, int ntiles)
{
    __shared__ unsigned int hsh[4][16][68]; // per-wave h tile, 272B rows (16B-aligned)
    __shared__ float sOut[4][256];          // per-wave epilogue staging [lp][ch]

    const int tid  = threadIdx.x;
    const int wave = tid >> 6;
    const int lane = tid & 63;
    const int l15 = lane & 15;
    const int quad = lane >> 4;

    // B1 fragments straight from global: W1[k][n], k = quad*8+j, n = 16nt+l15
    bf16x8 B1[8];
#pragma unroll
    for (int nt = 0; nt < 8; nt++) {
        int col = nt * 16 + l15;
        const float* w = (col < 64) ? (dw1 + col) : (fw1 + (col - 64));
#pragma unroll
        for (int j = 0; j < 8; j++) {
            int k = quad * 8 + j;
            B1[nt][j] = f32_to_bf16_s(w[k * 64]);
        }
    }

    // B2 fragments: rows permuted by hu(k_lds) = 16*(k_lds&7) + (k_lds>>3)
    bf16x8 B2[4];
#pragma unroll
    for (int s = 0; s < 4; s++) {
#pragma unroll
        for (int j = 0; j < 8; j++) {
            int k_lds = s * 32 + quad * 8 + j;
            int hu = ((k_lds & 7) << 4) | (k_lds >> 3);
            float v = 0.0f;
            if (l15 == 0)      v = (hu < 64)  ? dw2[hu] : 0.0f;
            else if (l15 < 4)  v = (hu >= 64) ? fw2[(hu - 64) * 3 + (l15 - 1)] : 0.0f;
            B2[s][j] = f32_to_bf16_s(v);
        }
    }

    for (int tile = blockIdx.x; tile < ntiles; tile += gridDim.x) {
        const int wbase = tile * 256 + wave * 64;

        // all 16 A-fragment loads upfront (4 subtiles x 4 dwords)
        unsigned int au[4][4];
#pragma unroll
        for (int sub = 0; sub < 4; sub++) {
            int ptc = min(wbase + sub * 16 + l15, N - 1);
#pragma unroll
            for (int j = 0; j < 4; j++)
                au[sub][j] = enc[(size_t)(quad * 4 + j) * N + ptc];
        }

#pragma unroll
        for (int sub = 0; sub < 4; sub++) {
            union { unsigned int u[4]; bf16x8 v; } acvt;
#pragma unroll
            for (int j = 0; j < 4; j++) acvt.u[j] = au[sub][j];

            f32x4 acc1[8];
#pragma unroll
            for (int nt = 0; nt < 8; nt++) {
                acc1[nt] = (f32x4){0.0f, 0.0f, 0.0f, 0.0f};
                acc1[nt] = __builtin_amdgcn_mfma_f32_16x16x32_bf16(acvt.v, B1[nt], acc1[nt], 0, 0, 0);
            }

            // ReLU -> bf16 -> LDS: pack lane's 8 values, ONE b128 write per r
#pragma unroll
            for (int r = 0; r < 4; r++) {
                u32x4 pk;
#pragma unroll
                for (int d = 0; d < 4; d++) {
                    float h0 = fmaxf(acc1[2 * d + 0][r], 0.0f);
                    float h1 = fmaxf(acc1[2 * d + 1][r], 0.0f);
                    pk[d] = pack_bf16(h0, h1);
                }
                *(u32x4*)&hsh[wave][quad * 4 + r][l15 * 4] = pk;
            }

            // layer 2: 4 independent partial MFMAs
            f32x4 p0 = (f32x4){0,0,0,0}, p1 = (f32x4){0,0,0,0};
            f32x4 p2 = (f32x4){0,0,0,0}, p3 = (f32x4){0,0,0,0};
            {
                bf16x8 a0 = *(const bf16x8*)&hsh[wave][l15][0 * 16 + quad * 4];
                bf16x8 a1 = *(const bf16x8*)&hsh[wave][l15][1 * 16 + quad * 4];
                bf16x8 a2 = *(const bf16x8*)&hsh[wave][l15][2 * 16 + quad * 4];
                bf16x8 a3 = *(const bf16x8*)&hsh[wave][l15][3 * 16 + quad * 4];
                p0 = __builtin_amdgcn_mfma_f32_16x16x32_bf16(a0, B2[0], p0, 0, 0, 0);
                p1 = __builtin_amdgcn_mfma_f32_16x16x32_bf16(a1, B2[1], p1, 0, 0, 0);
                p2 = __builtin_amdgcn_mfma_f32_16x16x32_bf16(a2, B2[2], p2, 0, 0, 0);
                p3 = __builtin_amdgcn_mfma_f32_16x16x32_bf16(a3, B2[3], p3, 0, 0, 0);
            }
            f32x4 acc2;
#pragma unroll
            for (int r = 0; r < 4; r++) acc2[r] = (p0[r] + p1[r]) + (p2[r] + p3[r]);

            // stage acc2: sOut[wave][(sub*16 + p16)*4 + ch]; ch0=density,1..3=rgb
            if (l15 < 4) {
#pragma unroll
                for (int r = 0; r < 4; r++)
                    sOut[wave][(sub * 16 + quad * 4 + r) * 4 + l15] = acc2[r];
            }
        }

        // batched coalesced epilogue: 192 colors + 64 densities per wave
        long long cmax = ((long long)N - wbase) * 3;
#pragma unroll
        for (int round = 0; round < 3; round++) {
            int f = round * 64 + lane;
            int lp = f / 3, c = f - lp * 3;
            float v = sOut[wave][lp * 4 + 1 + c];
            v = 1.0f / (1.0f + expf(-v));
            if (f < cmax) out[(size_t)wbase * 3 + f] = v;
        }
        {
            int p = wbase + lane;
            float v = sOut[wave][lane * 4];
            v = (v > 20.0f) ? v : log1pf(expf(v));
            if (p < N) out[(size_t)3 * N + p] = v;
        }
    }
}

// ---------- fallback: round-1 fused kernel (used only if ws too small) ----------
__global__ __launch_bounds__(256) void nerf_fused(
    const float* __restrict__ points,
    const float* __restrict__ table,
    const float* __restrict__ dw1, const float* __restrict__ dw2,
    const float* __restrict__ fw1, const float* __restrict__ fw2,
    float* __restrict__ out, int N, LevelConsts C)
{
    __shared__ float sD[64 * 32];
    __shared__ float sF[64 * 32];
    __shared__ float sDw2[64];
    __shared__ float sFw2[64 * 3];

    for (int idx = threadIdx.x; idx < 2048; idx += 256) {
        int i = idx >> 6;
        int j = idx & 63;
        sD[j * 32 + i] = dw1[idx];
        sF[j * 32 + i] = fw1[idx];
    }
    if (threadIdx.x < 64)  sDw2[threadIdx.x] = dw2[threadIdx.x];
    if (threadIdx.x < 192) sFw2[threadIdx.x] = fw2[threadIdx.x];
    __syncthreads();

    int gid = blockIdx.x * 256 + threadIdx.x;
    if (gid >= N) return;

    float px = points[gid * 3 + 0];
    float py = points[gid * 3 + 1];
    float pz = points[gid * 3 + 2];
    float x = fminf(fmaxf((px + 1.0f) * 0.5f, 0.0f), 1.0f);
    float y = fminf(fmaxf((py + 1.0f) * 0.5f, 0.0f), 1.0f);
    float z = fminf(fmaxf((pz + 1.0f) * 0.5f, 0.0f), 1.0f);

    float enc[32];

#pragma unroll
    for (int l = 0; l < NLV; l++) {
        const float sc = C.scale[l];
        const int   res = C.res[l];
        const int   dense = C.dense[l];
        const float* __restrict__ tbl = table + (size_t)l * TBL_SIZE * 2;

        float fx = x * sc + 0.5f;
        float fy = y * sc + 0.5f;
        float fz = z * sc + 0.5f;
        float f0x = floorf(fx), f0y = floorf(fy), f0z = floorf(fz);
        float wx = fx - f0x, wy = fy - f0y, wz = fz - f0z;
        int ix0 = min(max((int)f0x, 0), res - 1);
        int iy0 = min(max((int)f0y, 0), res - 1);
        int iz0 = min(max((int)f0z, 0), res - 1);
        int ix1 = min(ix0 + 1, res - 1);
        int iy1 = min(iy0 + 1, res - 1);
        int iz1 = min(iz0 + 1, res - 1);

        float e0 = 0.0f, e1 = 0.0f;
#pragma unroll
        for (int c = 0; c < 8; c++) {
            int cx = (c & 4) ? ix1 : ix0;
            int cy = (c & 2) ? iy1 : iy0;
            int cz = (c & 1) ? iz1 : iz0;
            float wgt = (((c & 4) ? wx : 1.0f - wx) *
                         ((c & 2) ? wy : 1.0f - wy)) *
                         ((c & 1) ? wz : 1.0f - wz);
            unsigned int idx;
            if (dense) {
                idx = (unsigned int)(cx + res * cy + res * res * cz);
            } else {
                idx = ((unsigned int)cx * 1u
                     ^ (unsigned int)cy * 2654435761u
                     ^ (unsigned int)cz * 805459861u) & (TBL_SIZE - 1u);
            }
            const float2 g = *(const float2*)(tbl + (size_t)idx * 2);
            e0 = fmaf(wgt, g.x, e0);
            e1 = fmaf(wgt, g.y, e1);
        }
        enc[2 * l + 0] = e0;
        enc[2 * l + 1] = e1;
    }

    float dacc = 0.0f, c0 = 0.0f, c1 = 0.0f, c2 = 0.0f;
    for (int j = 0; j < 64; j++) {
        float hd = 0.0f, hf = 0.0f;
        const float* __restrict__ colD = &sD[j * 32];
        const float* __restrict__ colF = &sF[j * 32];
#pragma unroll
        for (int i = 0; i < 32; i++) {
            hd = fmaf(enc[i], colD[i], hd);
            hf = fmaf(enc[i], colF[i], hf);
        }
        hd = fmaxf(hd, 0.0f);
        hf = fmaxf(hf, 0.0f);
        dacc = fmaf(hd, sDw2[j], dacc);
        c0 = fmaf(hf, sFw2[j * 3 + 0], c0);
        c1 = fmaf(hf, sFw2[j * 3 + 1], c1);
        c2 = fmaf(hf, sFw2[j * 3 + 2], c2);
    }

    float density = (dacc > 20.0f) ? dacc : log1pf(expf(dacc));
    out[gid * 3 + 0] = 1.0f / (1.0f + expf(-c0));
    out[gid * 3 + 1] = 1.0f / (1.0f + expf(-c1));
    out[gid * 3 + 2] = 1.0f / (1.0f + expf(-c2));
    out[(size_t)3 * N + gid] = density;
}

extern "C" void kernel_launch(void* const* d_in, const int* in_sizes, int n_in,
                              void* d_out, int out_size, void* d_ws, size_t ws_size,
                              hipStream_t stream) {
    const float* points = (const float*)d_in[0];
    const float* table  = (const float*)d_in[1];
    const float* dw1    = (const float*)d_in[2];
    const float* dw2    = (const float*)d_in[3];
    const float* fw1    = (const float*)d_in[4];
    const float* fw2    = (const float*)d_in[5];
    int N = in_sizes[0] / 3;

    LevelConsts C;
    for (int l = 0; l < NLV; l++) {
        double s = 16.0 * pow(1.447269237440378, (double)l) - 1.0;
        C.scale[l] = (float)s;
        int res = (int)ceil(s) + 1;
        C.res[l] = res;
        C.dense[l] = ((long long)res * res * res <= (long long)TBL_SIZE) ? 1 : 0;
    }

    const size_t tbl_bytes = (size_t)NLV * TBL_SIZE * 4;      // 32 MB packed bf16
    const size_t enc_bytes = (size_t)N * NLV * 4;             // 64 MB level-major
    if (ws_size >= tbl_bytes + enc_bytes) {
        unsigned int* tbl_bf16 = (unsigned int*)d_ws;
        unsigned int* enc_ws   = (unsigned int*)((char*)d_ws + tbl_bytes);

        int npairs = NLV * TBL_SIZE;
        cvt_table<<<1024, 256, 0, stream>>>(table, tbl_bf16, npairs);

        int chunks = (N + 256 * ENC_P - 1) / (256 * ENC_P);
        encode_lvl<<<dim3(chunks, NLV), 256, 0, stream>>>(points, tbl_bf16, enc_ws, N, C);

        int ntiles = (N + 255) / 256;
        mlp_kernel<<<1792, 256, 0, stream>>>(enc_ws, dw1, dw2, fw1, fw2,
                                             (float*)d_out, N, ntiles);
    } else {
        int blocks = (N + 255) / 256;
        nerf_fused<<<blocks, 256, 0, stream>>>(points, table, dw1, dw2, fw1, fw2,
                                               (float*)d_out, N, C);
    }
}